// Round 1
// baseline (147.367 us; speedup 1.0000x reference)
//
#include <hip/hip_runtime.h>

// Embedding-bag: out[b,:] = bias + sum_k vals[b,k] * weight[ics[b,k],:]
// B=16384, K=32, N_OUT=256 (64 float4 per row -> one wave per row).

constexpr int K = 32;
constexpr int NOUT4 = 64;  // 256 floats / 4

__global__ __launch_bounds__(256) void FeatureTransformer_45896020525219_kernel(
    const int* __restrict__ ics,
    const float* __restrict__ vals,
    const float4* __restrict__ w4,
    const float4* __restrict__ bias4,
    float4* __restrict__ out4,
    int B)
{
    const int lane = threadIdx.x & 63;
    const int wave = threadIdx.x >> 6;
    const int b = blockIdx.x * 4 + wave;
    if (b >= B) return;

    // Lane i (and i+32) holds index/value for k = i&31; K-loop broadcasts
    // via readlane so the gather base is scalar (SGPR) per iteration.
    const int kk = lane & 31;
    int   my_idx = ics[b * K + kk];
    float my_val = vals[b * K + kk];

    float4 acc = bias4[lane];

    #pragma unroll
    for (int k = 0; k < K; ++k) {
        const int j = __builtin_amdgcn_readlane(my_idx, k);           // wave-uniform
        const float v = __uint_as_float(
            __builtin_amdgcn_readlane(__float_as_uint(my_val), k));   // wave-uniform
        if (j >= 0) {  // -1 padding: scalar branch, no divergence
            const float4 w = w4[(size_t)j * NOUT4 + lane];            // 1 KiB coalesced
            acc.x = fmaf(v, w.x, acc.x);
            acc.y = fmaf(v, w.y, acc.y);
            acc.z = fmaf(v, w.z, acc.z);
            acc.w = fmaf(v, w.w, acc.w);
        }
    }

    out4[(size_t)b * NOUT4 + lane] = acc;
}

extern "C" void kernel_launch(void* const* d_in, const int* in_sizes, int n_in,
                              void* d_out, int out_size, void* d_ws, size_t ws_size,
                              hipStream_t stream) {
    const int*    ics   = (const int*)d_in[0];
    const float*  vals  = (const float*)d_in[1];
    const float4* w4    = (const float4*)d_in[2];
    const float4* bias4 = (const float4*)d_in[3];
    float4*       out4  = (float4*)d_out;

    const int B = in_sizes[0] / K;                 // 16384
    const int blocks = (B + 3) / 4;                // 4 waves (rows) per block

    hipLaunchKernelGGL(FeatureTransformer_45896020525219_kernel,
                       dim3(blocks), dim3(256), 0, stream,
                       ics, vals, w4, bias4, out4, B);
}

// Round 2
// 126.204 us; speedup vs baseline: 1.1677x; 1.1677x over previous
//
#include <hip/hip_runtime.h>

// Embedding-bag: out[b,:] = bias + sum_k vals[b,k] * weight[ics[b,k],:]
// B=16384, K=32, N_OUT=256.
//
// Layout: 8 column-slices of 32 cols; slice = blockIdx % 8 -> pins each
// slice to one XCD (round-robin dispatch heuristic), shrinking the per-XCD
// gather working set to 41024*32*4B = 5.25 MiB (~L2-resident vs 40 MiB table).
// Wave = 8 rows x 8 lanes (float4 each); indices prefetched as int4 and
// broadcast with __shfl; padding masked branchlessly so all 32 gathers
// pipeline (many loads in flight per wave).

constexpr int K = 32;

__global__ __launch_bounds__(256) void FeatureTransformer_45896020525219_kernel(
    const int* __restrict__ ics,
    const float* __restrict__ vals,
    const float4* __restrict__ w4,     // [N_IN * 64]
    const float4* __restrict__ bias4,  // [64]
    float4* __restrict__ out4,         // [B * 64]
    int B)
{
    const int lane   = threadIdx.x & 63;
    const int wave   = threadIdx.x >> 6;
    const int slice  = blockIdx.x & 7;   // -> XCD (locality heuristic only)
    const int rowblk = blockIdx.x >> 3;

    const int r  = lane >> 3;            // local row 0..7
    const int c4 = lane & 7;             // float4-column within the 32-col slice
    const int b  = rowblk * 32 + wave * 8 + r;
    if (b >= B) return;

    const int colbase = slice * 8 + c4;  // float4 index within the 64 per row

    // Lane holds k-quad c4 of its row's indices/values (coalesced 128B per row).
    const int4   idx4 = ((const int4*)  (ics  + b * K))[c4];
    const float4 v4   = ((const float4*)(vals + b * K))[c4];

    float4 acc = bias4[colbase];

    #pragma unroll
    for (int k = 0; k < K; ++k) {
        const int src = (lane & 56) | (k >> 2);  // lane in my row-group holding k
        const int   sel = k & 3;                 // compile-time in unrolled loop
        const int   jc  = sel == 0 ? idx4.x : sel == 1 ? idx4.y
                        : sel == 2 ? idx4.z : idx4.w;
        const float vc  = sel == 0 ? v4.x   : sel == 1 ? v4.y
                        : sel == 2 ? v4.z   : v4.w;
        const int   jj = __shfl(jc, src);
        const float vs = __shfl(vc, src);

        const float    v = (jj >= 0) ? vs : 0.0f;          // branchless padding
        const unsigned j = (jj >= 0) ? (unsigned)jj : 0u;

        const float4 w = w4[(size_t)j * 64 + colbase];     // 128B per row-group
        acc.x = fmaf(v, w.x, acc.x);
        acc.y = fmaf(v, w.y, acc.y);
        acc.z = fmaf(v, w.z, acc.z);
        acc.w = fmaf(v, w.w, acc.w);
    }

    out4[(size_t)b * 64 + colbase] = acc;
}

extern "C" void kernel_launch(void* const* d_in, const int* in_sizes, int n_in,
                              void* d_out, int out_size, void* d_ws, size_t ws_size,
                              hipStream_t stream) {
    const int*    ics   = (const int*)d_in[0];
    const float*  vals  = (const float*)d_in[1];
    const float4* w4    = (const float4*)d_in[2];
    const float4* bias4 = (const float4*)d_in[3];
    float4*       out4  = (float4*)d_out;

    const int B = in_sizes[0] / K;            // 16384
    // 32 rows per block, 8 column-slices -> B/32*8 blocks
    const int blocks = ((B + 31) / 32) * 8;   // 4096

    hipLaunchKernelGGL(FeatureTransformer_45896020525219_kernel,
                       dim3(blocks), dim3(256), 0, stream,
                       ics, vals, w4, bias4, out4, B);
}

// Round 3
// 125.795 us; speedup vs baseline: 1.1715x; 1.0032x over previous
//
#include <hip/hip_runtime.h>

// Embedding-bag: out[b,:] = bias + sum_k vals[b,k] * weight[ics[b,k],:]
// B=16384, K=32, N_OUT=256.
//
// - 8 column-slices of 32 cols; slice = blockIdx % 8 -> XCD round-robin,
//   per-XCD gather slab = 41024*32*4B = 5.25 MiB (~81% L2 hit, measured R2).
// - Wave = 8 rows x 8 lanes (float4 each); indices int4-prefetched and
//   broadcast via __shfl; padding masked branchlessly.
// - K-loop in 4 chunks of 8 with explicit float4 wv[8] batches: 8 gathers
//   in flight per wave (R2's VGPR=36 showed the compiler only kept ~4;
//   latency-bound at 60 cyc/gather-instr).

constexpr int K = 32;

__global__ __launch_bounds__(256) void FeatureTransformer_45896020525219_kernel(
    const int* __restrict__ ics,
    const float* __restrict__ vals,
    const float4* __restrict__ w4,     // [N_IN * 64]
    const float4* __restrict__ bias4,  // [64]
    float4* __restrict__ out4,         // [B * 64]
    int B)
{
    const int lane   = threadIdx.x & 63;
    const int wave   = threadIdx.x >> 6;
    const int slice  = blockIdx.x & 7;   // -> XCD (locality heuristic)
    const int rowblk = blockIdx.x >> 3;

    const int r  = lane >> 3;            // local row 0..7
    const int c4 = lane & 7;             // float4-column within the 32-col slice
    const int b  = rowblk * 32 + wave * 8 + r;
    if (b >= B) return;

    const int colbase = slice * 8 + c4;  // float4 index within the 64 per row

    // Lane holds k-quad c4 of its row's indices/values (coalesced 128B/row).
    const int4   idx4 = ((const int4*)  (ics  + b * K))[c4];
    const float4 v4   = ((const float4*)(vals + b * K))[c4];

    float4 acc = bias4[colbase];

    #pragma unroll
    for (int c = 0; c < 4; ++c) {
        float4 wv[8];
        float  vv[8];
        #pragma unroll
        for (int u = 0; u < 8; ++u) {
            const int k   = c * 8 + u;
            const int src = (lane & 56) | (k >> 2);  // lane in row-group holding k
            const int sel = k & 3;                   // compile-time constant
            const int   jc = sel == 0 ? idx4.x : sel == 1 ? idx4.y
                           : sel == 2 ? idx4.z : idx4.w;
            const float vc = sel == 0 ? v4.x   : sel == 1 ? v4.y
                           : sel == 2 ? v4.z   : v4.w;
            const int   jj = __shfl(jc, src);
            const float vs = __shfl(vc, src);

            vv[u] = (jj >= 0) ? vs : 0.0f;           // branchless padding
            const unsigned j = (jj >= 0) ? (unsigned)jj : 0u;
            wv[u] = w4[(size_t)j * 64 + colbase];    // 8 gathers batched in flight
        }
        #pragma unroll
        for (int u = 0; u < 8; ++u) {
            acc.x = fmaf(vv[u], wv[u].x, acc.x);
            acc.y = fmaf(vv[u], wv[u].y, acc.y);
            acc.z = fmaf(vv[u], wv[u].z, acc.z);
            acc.w = fmaf(vv[u], wv[u].w, acc.w);
        }
    }

    out4[(size_t)b * 64 + colbase] = acc;
}

extern "C" void kernel_launch(void* const* d_in, const int* in_sizes, int n_in,
                              void* d_out, int out_size, void* d_ws, size_t ws_size,
                              hipStream_t stream) {
    const int*    ics   = (const int*)d_in[0];
    const float*  vals  = (const float*)d_in[1];
    const float4* w4    = (const float4*)d_in[2];
    const float4* bias4 = (const float4*)d_in[3];
    float4*       out4  = (float4*)d_out;

    const int B = in_sizes[0] / K;            // 16384
    const int blocks = ((B + 31) / 32) * 8;   // 32 rows/block x 8 slices = 4096

    hipLaunchKernelGGL(FeatureTransformer_45896020525219_kernel,
                       dim3(blocks), dim3(256), 0, stream,
                       ics, vals, w4, bias4, out4, B);
}